// Round 1
// baseline (509.029 us; speedup 1.0000x reference)
//
#include <hip/hip_runtime.h>
#include <math.h>

// Sizes (fixed by the reference)
#define Zc   4
#define Nc   128
#define EMBc 16
#define L0c  32
#define MLPHc 64
#define GEOc 64
#define NBc  32
#define NHc  128
#define Cc   128   // MLPH + GEO

// activations: sp(x) = softplus(5x)/5 ; ssp = sp - log(2)/5
__device__ __forceinline__ float sp5(float x){
    float y = 5.0f * x;
    float t = fabsf(y);
    return (fmaxf(y, 0.0f) + log1pf(__expf(-t))) * 0.2f;
}
__device__ __forceinline__ float ssp5(float x){
    return sp5(x) - 0.13862943611198906f;
}

// ---------------------------------------------------------------------------
// ResnetPointnet per atom + embedding lookup.  grid = Z*N blocks, 64 threads.
__global__ __launch_bounds__(64) void k_pointnet(
    const float* __restrict__ geom, const float* __restrict__ mask,
    const float* __restrict__ pw0, const float* __restrict__ pb0,
    const float* __restrict__ w1a, const float* __restrict__ b1a,
    const float* __restrict__ w1b, const float* __restrict__ b1b,
    const float* __restrict__ w2a, const float* __restrict__ b2a,
    const float* __restrict__ w2b, const float* __restrict__ b2b,
    const int*   __restrict__ features, const float* __restrict__ emb,
    float* __restrict__ geo_pn, float* __restrict__ f0)
{
    int zn = blockIdx.x;
    int c  = threadIdx.x;            // 0..63
    __shared__ float cur[GEOc];
    __shared__ float tmp[GEOc];
    float gx = geom[zn*3+0], gy = geom[zn*3+1], gz = geom[zn*3+2];
    float v = fmaf(gx, pw0[0*GEOc+c], fmaf(gy, pw0[1*GEOc+c], fmaf(gz, pw0[2*GEOc+c], pb0[c])));
    const float* WA[2] = {w1a, w2a}; const float* BA[2] = {b1a, b2a};
    const float* WB[2] = {w1b, w2b}; const float* BB[2] = {b1b, b2b};
    #pragma unroll
    for (int blk = 0; blk < 2; blk++){
        cur[c] = v;
        __syncthreads();
        float s = BA[blk][c];
        for (int k = 0; k < GEOc; k++) s = fmaf(fmaxf(cur[k], 0.0f), WA[blk][k*GEOc+c], s);
        tmp[c] = s;
        __syncthreads();
        float s2 = BB[blk][c];
        for (int k = 0; k < GEOc; k++) s2 = fmaf(fmaxf(tmp[k], 0.0f), WB[blk][k*GEOc+c], s2);
        v = v + s2;
        __syncthreads();
    }
    geo_pn[zn*GEOc + c] = v * mask[zn];
    if (c < EMBc){
        int fi = features[zn];
        f0[zn*EMBc + c] = emb[fi*EMBc + c];
    }
}

// ---------------------------------------------------------------------------
// g[z,b,m,i] = sum_j w2[m, i*DIN+j] * f[z,b,j] * mask[z,b] * Y0/(sqrt(NH)*sqrt(N))
// layout: g[((z*N + b)*NH + m)*DOUT + i].  grid = Z*N/8 blocks, 256 threads.
template<int DIN, int DOUT>
__global__ __launch_bounds__(256) void k_gmat(
    const float* __restrict__ f, const float* __restrict__ mask,
    const float* __restrict__ w2, float* __restrict__ g)
{
    __shared__ float fsh[8][DIN];
    int t   = threadIdx.x;
    int zb0 = blockIdx.x * 8;
    if (t < 8*DIN){
        int r = t / DIN, j = t % DIN;
        int zb = zb0 + r;
        // Y0/128 = 0.2820947917738781 / 128
        fsh[r][j] = f[zb*DIN + j] * mask[zb] * 0.0022038655607334227f;
    }
    __syncthreads();
    for (int mi = t; mi < NHc*DOUT; mi += 256){
        int m_ = mi / DOUT, i_ = mi % DOUT;
        const float* wrow = w2 + (size_t)(m_*DOUT + i_)*DIN;
        float s[8];
        #pragma unroll
        for (int r = 0; r < 8; r++) s[r] = 0.0f;
        for (int j = 0; j < DIN; j++){
            float w = wrow[j];
            #pragma unroll
            for (int r = 0; r < 8; r++) s[r] = fmaf(fsh[r][j], w, s[r]);
        }
        #pragma unroll
        for (int r = 0; r < 8; r++)
            g[((size_t)(zb0 + r)*NHc + m_)*DOUT + i_] = s[r];
    }
}

// ---------------------------------------------------------------------------
// Fused per-pair radial MLP: basis(32) -> ssp(128) -> ssp(128) -> h2 (global).
// One block = 64 pairs (fixed z,a ; 64 consecutive b).  256 threads,
// each owns a 4-row x 8-col register tile of the 64x128 output.
__global__ __launch_bounds__(256) void k_pairmlp(
    const float* __restrict__ geom,
    const float* __restrict__ w0, const float* __restrict__ w1,
    float* __restrict__ h2)
{
    __shared__ float rsh[64];
    __shared__ float bas[64*33];    // padded stride 33: conflict-free column reads
    __shared__ float h1s[64*133];   // padded stride 133
    int t   = threadIdx.x;
    int p0  = blockIdx.x * 64;
    int z   = p0 >> 14;
    int rem = p0 & 16383;
    int a   = rem >> 7;
    int b0  = rem & 127;

    float ax = geom[(z*Nc + a)*3 + 0];
    float ay = geom[(z*Nc + a)*3 + 1];
    float az = geom[(z*Nc + a)*3 + 2];
    if (t < 64){
        int b = b0 + t;
        float dx = geom[(z*Nc + b)*3 + 0] - ax;
        float dy = geom[(z*Nc + b)*3 + 1] - ay;
        float dz = geom[(z*Nc + b)*3 + 2] - az;
        rsh[t] = sqrtf(dx*dx + dy*dy + dz*dz);
    }
    __syncthreads();

    const float step = 10.0f / 31.0f;
    #pragma unroll
    for (int j = 0; j < 8; j++){
        int idx = t + j*256;
        int p = idx >> 5, k = idx & 31;
        float x = (rsh[p] - (float)k * step) * 3.1f;   // /step
        float v = 0.0f;
        if (fabsf(x) < 1.0f){ float cc = __cosf(1.57079632679f * x); v = cc*cc; }
        bas[p*33 + k] = v;
    }
    __syncthreads();

    int rg = t >> 4;          // 16 row-groups of 4 rows
    int cg = t & 15;          // 16 col-groups of 8 cols
    int r0 = rg*4, c0 = cg*8;
    float acc[4][8];

    // phase 1: h1 = ssp(basis @ w0 / sqrt(32))
    #pragma unroll
    for (int r = 0; r < 4; r++)
        #pragma unroll
        for (int c = 0; c < 8; c++) acc[r][c] = 0.0f;
    for (int k = 0; k < NBc; k++){
        float4 wA = *reinterpret_cast<const float4*>(&w0[k*NHc + c0]);
        float4 wB = *reinterpret_cast<const float4*>(&w0[k*NHc + c0 + 4]);
        float hv[4];
        #pragma unroll
        for (int r = 0; r < 4; r++) hv[r] = bas[(r0 + r)*33 + k];
        #pragma unroll
        for (int r = 0; r < 4; r++){
            acc[r][0] = fmaf(hv[r], wA.x, acc[r][0]);
            acc[r][1] = fmaf(hv[r], wA.y, acc[r][1]);
            acc[r][2] = fmaf(hv[r], wA.z, acc[r][2]);
            acc[r][3] = fmaf(hv[r], wA.w, acc[r][3]);
            acc[r][4] = fmaf(hv[r], wB.x, acc[r][4]);
            acc[r][5] = fmaf(hv[r], wB.y, acc[r][5]);
            acc[r][6] = fmaf(hv[r], wB.z, acc[r][6]);
            acc[r][7] = fmaf(hv[r], wB.w, acc[r][7]);
        }
    }
    const float s0 = 0.17677669529663687f;  // 1/sqrt(32)
    #pragma unroll
    for (int r = 0; r < 4; r++)
        #pragma unroll
        for (int c = 0; c < 8; c++)
            h1s[(r0 + r)*133 + c0 + c] = ssp5(acc[r][c] * s0);
    __syncthreads();

    // phase 2: h2 = ssp(h1 @ w1 / sqrt(128))
    #pragma unroll
    for (int r = 0; r < 4; r++)
        #pragma unroll
        for (int c = 0; c < 8; c++) acc[r][c] = 0.0f;
    for (int k = 0; k < NHc; k++){
        float4 wA = *reinterpret_cast<const float4*>(&w1[k*NHc + c0]);
        float4 wB = *reinterpret_cast<const float4*>(&w1[k*NHc + c0 + 4]);
        float hv[4];
        #pragma unroll
        for (int r = 0; r < 4; r++) hv[r] = h1s[(r0 + r)*133 + k];
        #pragma unroll
        for (int r = 0; r < 4; r++){
            acc[r][0] = fmaf(hv[r], wA.x, acc[r][0]);
            acc[r][1] = fmaf(hv[r], wA.y, acc[r][1]);
            acc[r][2] = fmaf(hv[r], wA.z, acc[r][2]);
            acc[r][3] = fmaf(hv[r], wA.w, acc[r][3]);
            acc[r][4] = fmaf(hv[r], wB.x, acc[r][4]);
            acc[r][5] = fmaf(hv[r], wB.y, acc[r][5]);
            acc[r][6] = fmaf(hv[r], wB.z, acc[r][6]);
            acc[r][7] = fmaf(hv[r], wB.w, acc[r][7]);
        }
    }
    const float s1 = 0.08838834764831845f;  // 1/sqrt(128)
    size_t base = ((size_t)(z*Nc + a)*Nc + b0) * NHc;
    #pragma unroll
    for (int r = 0; r < 4; r++){
        float4 o;
        o.x = ssp5(acc[r][0]*s1); o.y = ssp5(acc[r][1]*s1);
        o.z = ssp5(acc[r][2]*s1); o.w = ssp5(acc[r][3]*s1);
        *reinterpret_cast<float4*>(&h2[base + (size_t)(r0 + r)*NHc + c0]) = o;
        o.x = ssp5(acc[r][4]*s1); o.y = ssp5(acc[r][5]*s1);
        o.z = ssp5(acc[r][6]*s1); o.w = ssp5(acc[r][7]*s1);
        *reinterpret_cast<float4*>(&h2[base + (size_t)(r0 + r)*NHc + c0 + 4]) = o;
    }
}

// ---------------------------------------------------------------------------
// f_partial[s][z][a][i] = sum_{bm in slice s} h2[z,a,bm] * g[z,bm,i]
// grid = (16 slices, 8 a-tiles, Z), 256 threads.  K = N*NH = 16384, 1024/slice.
template<int DOUT>
__global__ __launch_bounds__(256) void k_gemm3(
    const float* __restrict__ h2, const float* __restrict__ g,
    float* __restrict__ partial)
{
    constexpr int AL = DOUT / 16;       // a's per thread (4 or 2)
    __shared__ float h2sh[16*256];      // 16 a-rows x 256 bm
    int t  = threadIdx.x;
    int s  = blockIdx.x;                // 0..15
    int at = blockIdx.y;                // 0..7
    int z  = blockIdx.z;
    int a0 = at * 16;
    int bm0 = s * 1024;
    int i  = t % DOUT;
    int ag = t / DOUT;
    float acc[AL];
    #pragma unroll
    for (int al = 0; al < AL; al++) acc[al] = 0.0f;
    const float* gz = g + (size_t)z * (Nc*NHc) * DOUT;
    for (int ch = 0; ch < 4; ch++){
        __syncthreads();
        #pragma unroll
        for (int j = 0; j < 16; j++){
            int idx = t + j*256;
            int r = idx >> 8, c = idx & 255;
            h2sh[idx] = h2[(size_t)(z*Nc + a0 + r)*(Nc*NHc) + bm0 + ch*256 + c];
        }
        __syncthreads();
        const float* gb = gz + (size_t)(bm0 + ch*256)*DOUT + i;
        for (int bb = 0; bb < 256; bb += 4){
            float4 hv[AL];
            #pragma unroll
            for (int al = 0; al < AL; al++)
                hv[al] = *reinterpret_cast<const float4*>(&h2sh[(ag*AL + al)*256 + bb]);
            #pragma unroll
            for (int q = 0; q < 4; q++){
                float gv = gb[(size_t)(bb + q)*DOUT];
                #pragma unroll
                for (int al = 0; al < AL; al++)
                    acc[al] = fmaf(reinterpret_cast<const float*>(&hv[al])[q], gv, acc[al]);
            }
        }
    }
    #pragma unroll
    for (int al = 0; al < AL; al++){
        int a = a0 + ag*AL + al;
        partial[(((size_t)s*Zc + z)*Nc + a)*DOUT + i] = acc[al];
    }
}

// f_next = sp(sum_s partial) * mask
template<int DOUT>
__global__ __launch_bounds__(256) void k_epilogue(
    const float* __restrict__ partial, const float* __restrict__ mask,
    float* __restrict__ fout)
{
    int idx = blockIdx.x*256 + threadIdx.x;
    if (idx >= Zc*Nc*DOUT) return;
    int zn = idx / DOUT;
    float s = 0.0f;
    #pragma unroll
    for (int sl = 0; sl < 16; sl++) s += partial[(size_t)sl*(Zc*Nc*DOUT) + idx];
    fout[idx] = sp5(s) * mask[zn];
}

// ---------------------------------------------------------------------------
// output MLP
__global__ __launch_bounds__(128) void k_x1(
    const float* __restrict__ f3, const float* __restrict__ geo_pn,
    const float* __restrict__ w, const float* __restrict__ b,
    float* __restrict__ x1)
{
    int zn = blockIdx.x;
    int c  = threadIdx.x;   // 128
    __shared__ float feat[Cc];
    feat[c] = (c < MLPHc) ? f3[zn*MLPHc + c] : geo_pn[zn*GEOc + (c - MLPHc)];
    __syncthreads();
    float s = b[c];
    for (int k = 0; k < Cc; k++) s = fmaf(feat[k], w[k*Cc + c], s);
    x1[zn*Cc + c] = s;
}

__global__ __launch_bounds__(256) void k_x2(
    const float* __restrict__ x1n, const float* __restrict__ w,
    const float* __restrict__ b, float* __restrict__ x2)
{
    int zn = blockIdx.x;
    int c  = threadIdx.x;   // 256
    __shared__ float row[Cc];
    if (c < Cc) row[c] = x1n[zn*Cc + c];
    __syncthreads();
    float s = b[c];
    for (int k = 0; k < Cc; k++) s = fmaf(row[k], w[k*2*Cc + c], s);
    x2[zn*2*Cc + c] = s;
}

// BatchNorm1d(natoms) over (Z, C) per atom slot + leaky, in place.
template<int CC>
__global__ __launch_bounds__(256) void k_bn(
    float* __restrict__ x, const float* __restrict__ gamma,
    const float* __restrict__ beta)
{
    int n = blockIdx.x;
    int t = threadIdx.x;
    __shared__ float ssum[4], ssq[4];
    float sum = 0.0f, sq = 0.0f;
    for (int idx = t; idx < Zc*CC; idx += 256){
        int z = idx / CC, c = idx % CC;
        float v = x[((size_t)z*Nc + n)*CC + c];
        sum += v; sq += v*v;
    }
    #pragma unroll
    for (int off = 32; off > 0; off >>= 1){
        sum += __shfl_down(sum, off);
        sq  += __shfl_down(sq,  off);
    }
    if ((t & 63) == 0){ ssum[t >> 6] = sum; ssq[t >> 6] = sq; }
    __syncthreads();
    float tot  = ssum[0] + ssum[1] + ssum[2] + ssum[3];
    float totq = ssq[0]  + ssq[1]  + ssq[2]  + ssq[3];
    const float inv = 1.0f / (float)(Zc*CC);
    float mu   = tot * inv;
    float var  = totq * inv - mu*mu;
    float rstd = rsqrtf(var + 1e-5f);
    float ga = gamma[n], be = beta[n];
    for (int idx = t; idx < Zc*CC; idx += 256){
        int z = idx / CC, c = idx % CC;
        size_t o = ((size_t)z*Nc + n)*CC + c;
        float v = (x[o] - mu) * rstd * ga + be;
        x[o] = v > 0.0f ? v : 0.2f*v;
    }
}

__global__ __launch_bounds__(256) void k_out(
    const float* __restrict__ x2n, const float* __restrict__ mask,
    float* __restrict__ out)
{
    int z = blockIdx.x;
    int c = threadIdx.x;   // 256
    float s = 0.0f;
    for (int n = 0; n < Nc; n++)
        s += x2n[((size_t)z*Nc + n)*2*Cc + c] * mask[z*Nc + n];
    out[z*2*Cc + c] = s;
}

// ---------------------------------------------------------------------------
extern "C" void kernel_launch(void* const* d_in, const int* in_sizes, int n_in,
                              void* d_out, int out_size, void* d_ws, size_t ws_size,
                              hipStream_t stream)
{
    const int*   features = (const int*)  d_in[0];
    const float* geom     = (const float*)d_in[1];
    const float* mask     = (const float*)d_in[2];
    const float* emb      = (const float*)d_in[3];
    const float* rw[3][3] = {
        {(const float*)d_in[4],  (const float*)d_in[5],  (const float*)d_in[6]},
        {(const float*)d_in[7],  (const float*)d_in[8],  (const float*)d_in[9]},
        {(const float*)d_in[10], (const float*)d_in[11], (const float*)d_in[12]}};
    const float* pw0 = (const float*)d_in[13]; const float* pb0 = (const float*)d_in[14];
    const float* w1a = (const float*)d_in[15]; const float* b1a = (const float*)d_in[16];
    const float* w1b = (const float*)d_in[17]; const float* b1b = (const float*)d_in[18];
    const float* w2a = (const float*)d_in[19]; const float* b2a = (const float*)d_in[20];
    const float* w2b = (const float*)d_in[21]; const float* b2b = (const float*)d_in[22];
    const float* e1w = (const float*)d_in[23]; const float* e1b = (const float*)d_in[24];
    const float* bn1g= (const float*)d_in[25]; const float* bn1b= (const float*)d_in[26];
    const float* e2w = (const float*)d_in[27]; const float* e2b = (const float*)d_in[28];
    const float* bn2g= (const float*)d_in[29]; const float* bn2b= (const float*)d_in[30];

    // workspace layout (floats); total ~13.4M floats = ~53.6 MB
    float* ws     = (float*)d_ws;
    float* h2     = ws;                        // Z*N*N*NH       = 8388608
    float* g      = h2   + 8388608;            // Z*N*NH*64 max  = 4194304
    float* part   = g    + 4194304;            // 16*Z*N*64      =  524288
    float* fA     = part + 524288;             // Z*N*64
    float* fB     = fA   + 32768;
    float* geo_pn = fB   + 32768;
    float* x1     = geo_pn + 32768;            // Z*N*C
    float* x2     = x1   + 65536;              // Z*N*2C
    (void)ws_size; (void)in_sizes; (void)n_in; (void)out_size;

    k_pointnet<<<Zc*Nc, 64, 0, stream>>>(geom, mask, pw0, pb0, w1a, b1a, w1b, b1b,
                                         w2a, b2a, w2b, b2b, features, emb, geo_pn, fA);

    // layer 0: din=16(EMB), dout=32(L0)
    k_gmat<16,32><<<Zc*Nc/8, 256, 0, stream>>>(fA, mask, rw[0][2], g);
    k_pairmlp<<<Zc*Nc*Nc/64, 256, 0, stream>>>(geom, rw[0][0], rw[0][1], h2);
    k_gemm3<32><<<dim3(16,8,Zc), 256, 0, stream>>>(h2, g, part);
    k_epilogue<32><<<(Zc*Nc*32 + 255)/256, 256, 0, stream>>>(part, mask, fB);

    // layer 1: din=32, dout=32
    k_gmat<32,32><<<Zc*Nc/8, 256, 0, stream>>>(fB, mask, rw[1][2], g);
    k_pairmlp<<<Zc*Nc*Nc/64, 256, 0, stream>>>(geom, rw[1][0], rw[1][1], h2);
    k_gemm3<32><<<dim3(16,8,Zc), 256, 0, stream>>>(h2, g, part);
    k_epilogue<32><<<(Zc*Nc*32 + 255)/256, 256, 0, stream>>>(part, mask, fA);

    // layer 2: din=32, dout=64(MLPH)
    k_gmat<32,64><<<Zc*Nc/8, 256, 0, stream>>>(fA, mask, rw[2][2], g);
    k_pairmlp<<<Zc*Nc*Nc/64, 256, 0, stream>>>(geom, rw[2][0], rw[2][1], h2);
    k_gemm3<64><<<dim3(16,8,Zc), 256, 0, stream>>>(h2, g, part);
    k_epilogue<64><<<(Zc*Nc*64 + 255)/256, 256, 0, stream>>>(part, mask, fB);

    // output MLP + per-atom BN + masked sum
    k_x1<<<Zc*Nc, 128, 0, stream>>>(fB, geo_pn, e1w, e1b, x1);
    k_bn<Cc><<<Nc, 256, 0, stream>>>(x1, bn1g, bn1b);
    k_x2<<<Zc*Nc, 256, 0, stream>>>(x1, e2w, e2b, x2);
    k_bn<2*Cc><<<Nc, 256, 0, stream>>>(x2, bn2g, bn2b);
    k_out<<<Zc, 256, 0, stream>>>(x2, mask, (float*)d_out);
}

// Round 2
// 374.623 us; speedup vs baseline: 1.3588x; 1.3588x over previous
//
#include <hip/hip_runtime.h>
#include <math.h>

// Sizes (fixed by the reference)
#define Zc   4
#define Nc   128
#define EMBc 16
#define L0c  32
#define MLPHc 64
#define GEOc 64
#define NBc  32
#define NHc  128
#define Cc   128   // MLPH + GEO

// activations: sp(x) = softplus(5x)/5 ; ssp = sp - log(2)/5
__device__ __forceinline__ float sp5(float x){
    float y = 5.0f * x;
    float t = fabsf(y);
    return (fmaxf(y, 0.0f) + log1pf(__expf(-t))) * 0.2f;
}
__device__ __forceinline__ float ssp5(float x){
    return sp5(x) - 0.13862943611198906f;
}

// ---------------------------------------------------------------------------
// ResnetPointnet per atom + embedding lookup.  grid = Z*N blocks, 64 threads.
__global__ __launch_bounds__(64) void k_pointnet(
    const float* __restrict__ geom, const float* __restrict__ mask,
    const float* __restrict__ pw0, const float* __restrict__ pb0,
    const float* __restrict__ w1a, const float* __restrict__ b1a,
    const float* __restrict__ w1b, const float* __restrict__ b1b,
    const float* __restrict__ w2a, const float* __restrict__ b2a,
    const float* __restrict__ w2b, const float* __restrict__ b2b,
    const int*   __restrict__ features, const float* __restrict__ emb,
    float* __restrict__ geo_pn, float* __restrict__ f0)
{
    int zn = blockIdx.x;
    int c  = threadIdx.x;            // 0..63
    __shared__ float cur[GEOc];
    __shared__ float tmp[GEOc];
    float gx = geom[zn*3+0], gy = geom[zn*3+1], gz = geom[zn*3+2];
    float v = fmaf(gx, pw0[0*GEOc+c], fmaf(gy, pw0[1*GEOc+c], fmaf(gz, pw0[2*GEOc+c], pb0[c])));
    const float* WA[2] = {w1a, w2a}; const float* BA[2] = {b1a, b2a};
    const float* WB[2] = {w1b, w2b}; const float* BB[2] = {b1b, b2b};
    #pragma unroll
    for (int blk = 0; blk < 2; blk++){
        cur[c] = v;
        __syncthreads();
        float s = BA[blk][c];
        for (int k = 0; k < GEOc; k++) s = fmaf(fmaxf(cur[k], 0.0f), WA[blk][k*GEOc+c], s);
        tmp[c] = s;
        __syncthreads();
        float s2 = BB[blk][c];
        for (int k = 0; k < GEOc; k++) s2 = fmaf(fmaxf(tmp[k], 0.0f), WB[blk][k*GEOc+c], s2);
        v = v + s2;
        __syncthreads();
    }
    geo_pn[zn*GEOc + c] = v * mask[zn];
    if (c < EMBc){
        int fi = features[zn];
        f0[zn*EMBc + c] = emb[fi*EMBc + c];
    }
}

// ---------------------------------------------------------------------------
// g[z,b,m,i] = sum_j w2[m, i*DIN+j] * f[z,b,j] * mask[z,b] * Y0/(sqrt(NH)*sqrt(N))
// layout: g[((z*N + b)*NH + m)*DOUT + i] = g[zb*NH*DOUT + mi], mi = m*DOUT+i.
// grid = (Z*N/8, NH*DOUT/256), 256 threads; thread owns 1 mi x 8 zb-rows.
template<int DIN, int DOUT>
__global__ __launch_bounds__(256) void k_gmat(
    const float* __restrict__ f, const float* __restrict__ mask,
    const float* __restrict__ w2, float* __restrict__ g)
{
    __shared__ float fsh[8][DIN];
    int t   = threadIdx.x;
    int zb0 = blockIdx.x * 8;
    if (t < 8*DIN){
        int r = t / DIN, j = t % DIN;
        int zb = zb0 + r;
        // Y0/128 = 0.2820947917738781 / 128
        fsh[r][j] = f[zb*DIN + j] * mask[zb] * 0.0022038655607334227f;
    }
    __syncthreads();
    int mi = blockIdx.y * 256 + t;
    const float* wrow = w2 + (size_t)mi * DIN;
    float s[8];
    #pragma unroll
    for (int r = 0; r < 8; r++) s[r] = 0.0f;
    #pragma unroll
    for (int j4 = 0; j4 < DIN/4; j4++){
        float4 w = *reinterpret_cast<const float4*>(&wrow[j4*4]);
        #pragma unroll
        for (int q = 0; q < 4; q++){
            float wv = reinterpret_cast<const float*>(&w)[q];
            int j = j4*4 + q;
            #pragma unroll
            for (int r = 0; r < 8; r++)
                s[r] = fmaf(fsh[r][j], wv, s[r]);
        }
    }
    #pragma unroll
    for (int r = 0; r < 8; r++)
        g[(size_t)(zb0 + r)*(NHc*DOUT) + mi] = s[r];
}

// ---------------------------------------------------------------------------
// Fused per-pair radial MLP: basis(32) -> ssp(128) -> ssp(128) -> h2 (global).
// One block = 64 pairs (fixed z,a ; 64 consecutive b).  256 threads,
// each owns a 4-row x 8-col register tile of the 64x128 output.
__global__ __launch_bounds__(256) void k_pairmlp(
    const float* __restrict__ geom,
    const float* __restrict__ w0, const float* __restrict__ w1,
    float* __restrict__ h2)
{
    __shared__ float rsh[64];
    __shared__ float bas[64*33];    // padded stride 33: conflict-free column reads
    __shared__ float h1s[64*133];   // padded stride 133
    int t   = threadIdx.x;
    int p0  = blockIdx.x * 64;
    int z   = p0 >> 14;
    int rem = p0 & 16383;
    int a   = rem >> 7;
    int b0  = rem & 127;

    float ax = geom[(z*Nc + a)*3 + 0];
    float ay = geom[(z*Nc + a)*3 + 1];
    float az = geom[(z*Nc + a)*3 + 2];
    if (t < 64){
        int b = b0 + t;
        float dx = geom[(z*Nc + b)*3 + 0] - ax;
        float dy = geom[(z*Nc + b)*3 + 1] - ay;
        float dz = geom[(z*Nc + b)*3 + 2] - az;
        rsh[t] = sqrtf(dx*dx + dy*dy + dz*dz);
    }
    __syncthreads();

    const float step = 10.0f / 31.0f;
    #pragma unroll
    for (int j = 0; j < 8; j++){
        int idx = t + j*256;
        int p = idx >> 5, k = idx & 31;
        float x = (rsh[p] - (float)k * step) * 3.1f;   // /step
        float v = 0.0f;
        if (fabsf(x) < 1.0f){ float cc = __cosf(1.57079632679f * x); v = cc*cc; }
        bas[p*33 + k] = v;
    }
    __syncthreads();

    int rg = t >> 4;          // 16 row-groups of 4 rows
    int cg = t & 15;          // 16 col-groups of 8 cols
    int r0 = rg*4, c0 = cg*8;
    float acc[4][8];

    // phase 1: h1 = ssp(basis @ w0 / sqrt(32))
    #pragma unroll
    for (int r = 0; r < 4; r++)
        #pragma unroll
        for (int c = 0; c < 8; c++) acc[r][c] = 0.0f;
    for (int k = 0; k < NBc; k++){
        float4 wA = *reinterpret_cast<const float4*>(&w0[k*NHc + c0]);
        float4 wB = *reinterpret_cast<const float4*>(&w0[k*NHc + c0 + 4]);
        float hv[4];
        #pragma unroll
        for (int r = 0; r < 4; r++) hv[r] = bas[(r0 + r)*33 + k];
        #pragma unroll
        for (int r = 0; r < 4; r++){
            acc[r][0] = fmaf(hv[r], wA.x, acc[r][0]);
            acc[r][1] = fmaf(hv[r], wA.y, acc[r][1]);
            acc[r][2] = fmaf(hv[r], wA.z, acc[r][2]);
            acc[r][3] = fmaf(hv[r], wA.w, acc[r][3]);
            acc[r][4] = fmaf(hv[r], wB.x, acc[r][4]);
            acc[r][5] = fmaf(hv[r], wB.y, acc[r][5]);
            acc[r][6] = fmaf(hv[r], wB.z, acc[r][6]);
            acc[r][7] = fmaf(hv[r], wB.w, acc[r][7]);
        }
    }
    const float s0 = 0.17677669529663687f;  // 1/sqrt(32)
    #pragma unroll
    for (int r = 0; r < 4; r++)
        #pragma unroll
        for (int c = 0; c < 8; c++)
            h1s[(r0 + r)*133 + c0 + c] = ssp5(acc[r][c] * s0);
    __syncthreads();

    // phase 2: h2 = ssp(h1 @ w1 / sqrt(128))
    #pragma unroll
    for (int r = 0; r < 4; r++)
        #pragma unroll
        for (int c = 0; c < 8; c++) acc[r][c] = 0.0f;
    for (int k = 0; k < NHc; k++){
        float4 wA = *reinterpret_cast<const float4*>(&w1[k*NHc + c0]);
        float4 wB = *reinterpret_cast<const float4*>(&w1[k*NHc + c0 + 4]);
        float hv[4];
        #pragma unroll
        for (int r = 0; r < 4; r++) hv[r] = h1s[(r0 + r)*133 + k];
        #pragma unroll
        for (int r = 0; r < 4; r++){
            acc[r][0] = fmaf(hv[r], wA.x, acc[r][0]);
            acc[r][1] = fmaf(hv[r], wA.y, acc[r][1]);
            acc[r][2] = fmaf(hv[r], wA.z, acc[r][2]);
            acc[r][3] = fmaf(hv[r], wA.w, acc[r][3]);
            acc[r][4] = fmaf(hv[r], wB.x, acc[r][4]);
            acc[r][5] = fmaf(hv[r], wB.y, acc[r][5]);
            acc[r][6] = fmaf(hv[r], wB.z, acc[r][6]);
            acc[r][7] = fmaf(hv[r], wB.w, acc[r][7]);
        }
    }
    const float s1 = 0.08838834764831845f;  // 1/sqrt(128)
    size_t base = ((size_t)(z*Nc + a)*Nc + b0) * NHc;
    #pragma unroll
    for (int r = 0; r < 4; r++){
        float4 o;
        o.x = ssp5(acc[r][0]*s1); o.y = ssp5(acc[r][1]*s1);
        o.z = ssp5(acc[r][2]*s1); o.w = ssp5(acc[r][3]*s1);
        *reinterpret_cast<float4*>(&h2[base + (size_t)(r0 + r)*NHc + c0]) = o;
        o.x = ssp5(acc[r][4]*s1); o.y = ssp5(acc[r][5]*s1);
        o.z = ssp5(acc[r][6]*s1); o.w = ssp5(acc[r][7]*s1);
        *reinterpret_cast<float4*>(&h2[base + (size_t)(r0 + r)*NHc + c0 + 4]) = o;
    }
}

// ---------------------------------------------------------------------------
// f_partial[s][z][a][i] = sum_{bm in slice s} h2[z,a,bm] * g[z,bm,i]
// grid = (16 slices, 8 a-tiles, Z), 256 threads.  K = N*NH = 16384, 1024/slice.
template<int DOUT>
__global__ __launch_bounds__(256) void k_gemm3(
    const float* __restrict__ h2, const float* __restrict__ g,
    float* __restrict__ partial)
{
    constexpr int AL = DOUT / 16;       // a's per thread (4 or 2)
    __shared__ float h2sh[16*256];      // 16 a-rows x 256 bm
    int t  = threadIdx.x;
    int s  = blockIdx.x;                // 0..15
    int at = blockIdx.y;                // 0..7
    int z  = blockIdx.z;
    int a0 = at * 16;
    int bm0 = s * 1024;
    int i  = t % DOUT;
    int ag = t / DOUT;
    float acc[AL];
    #pragma unroll
    for (int al = 0; al < AL; al++) acc[al] = 0.0f;
    const float* gz = g + (size_t)z * (Nc*NHc) * DOUT;
    for (int ch = 0; ch < 4; ch++){
        __syncthreads();
        #pragma unroll
        for (int j = 0; j < 16; j++){
            int idx = t + j*256;
            int r = idx >> 8, c = idx & 255;
            h2sh[idx] = h2[(size_t)(z*Nc + a0 + r)*(Nc*NHc) + bm0 + ch*256 + c];
        }
        __syncthreads();
        const float* gb = gz + (size_t)(bm0 + ch*256)*DOUT + i;
        for (int bb = 0; bb < 256; bb += 4){
            float4 hv[AL];
            #pragma unroll
            for (int al = 0; al < AL; al++)
                hv[al] = *reinterpret_cast<const float4*>(&h2sh[(ag*AL + al)*256 + bb]);
            #pragma unroll
            for (int q = 0; q < 4; q++){
                float gv = gb[(size_t)(bb + q)*DOUT];
                #pragma unroll
                for (int al = 0; al < AL; al++)
                    acc[al] = fmaf(reinterpret_cast<const float*>(&hv[al])[q], gv, acc[al]);
            }
        }
    }
    #pragma unroll
    for (int al = 0; al < AL; al++){
        int a = a0 + ag*AL + al;
        partial[(((size_t)s*Zc + z)*Nc + a)*DOUT + i] = acc[al];
    }
}

// f_next = sp(sum_s partial) * mask
template<int DOUT>
__global__ __launch_bounds__(256) void k_epilogue(
    const float* __restrict__ partial, const float* __restrict__ mask,
    float* __restrict__ fout)
{
    int idx = blockIdx.x*256 + threadIdx.x;
    if (idx >= Zc*Nc*DOUT) return;
    int zn = idx / DOUT;
    float s = 0.0f;
    #pragma unroll
    for (int sl = 0; sl < 16; sl++) s += partial[(size_t)sl*(Zc*Nc*DOUT) + idx];
    fout[idx] = sp5(s) * mask[zn];
}

// ---------------------------------------------------------------------------
// output MLP
__global__ __launch_bounds__(128) void k_x1(
    const float* __restrict__ f3, const float* __restrict__ geo_pn,
    const float* __restrict__ w, const float* __restrict__ b,
    float* __restrict__ x1)
{
    int zn = blockIdx.x;
    int c  = threadIdx.x;   // 128
    __shared__ float feat[Cc];
    feat[c] = (c < MLPHc) ? f3[zn*MLPHc + c] : geo_pn[zn*GEOc + (c - MLPHc)];
    __syncthreads();
    float s = b[c];
    for (int k = 0; k < Cc; k++) s = fmaf(feat[k], w[k*Cc + c], s);
    x1[zn*Cc + c] = s;
}

__global__ __launch_bounds__(256) void k_x2(
    const float* __restrict__ x1n, const float* __restrict__ w,
    const float* __restrict__ b, float* __restrict__ x2)
{
    int zn = blockIdx.x;
    int c  = threadIdx.x;   // 256
    __shared__ float row[Cc];
    if (c < Cc) row[c] = x1n[zn*Cc + c];
    __syncthreads();
    float s = b[c];
    for (int k = 0; k < Cc; k++) s = fmaf(row[k], w[k*2*Cc + c], s);
    x2[zn*2*Cc + c] = s;
}

// BatchNorm1d(natoms) over (Z, C) per atom slot + leaky, in place.
template<int CC>
__global__ __launch_bounds__(256) void k_bn(
    float* __restrict__ x, const float* __restrict__ gamma,
    const float* __restrict__ beta)
{
    int n = blockIdx.x;
    int t = threadIdx.x;
    __shared__ float ssum[4], ssq[4];
    float sum = 0.0f, sq = 0.0f;
    for (int idx = t; idx < Zc*CC; idx += 256){
        int z = idx / CC, c = idx % CC;
        float v = x[((size_t)z*Nc + n)*CC + c];
        sum += v; sq += v*v;
    }
    #pragma unroll
    for (int off = 32; off > 0; off >>= 1){
        sum += __shfl_down(sum, off);
        sq  += __shfl_down(sq,  off);
    }
    if ((t & 63) == 0){ ssum[t >> 6] = sum; ssq[t >> 6] = sq; }
    __syncthreads();
    float tot  = ssum[0] + ssum[1] + ssum[2] + ssum[3];
    float totq = ssq[0]  + ssq[1]  + ssq[2]  + ssq[3];
    const float inv = 1.0f / (float)(Zc*CC);
    float mu   = tot * inv;
    float var  = totq * inv - mu*mu;
    float rstd = rsqrtf(var + 1e-5f);
    float ga = gamma[n], be = beta[n];
    for (int idx = t; idx < Zc*CC; idx += 256){
        int z = idx / CC, c = idx % CC;
        size_t o = ((size_t)z*Nc + n)*CC + c;
        float v = (x[o] - mu) * rstd * ga + be;
        x[o] = v > 0.0f ? v : 0.2f*v;
    }
}

__global__ __launch_bounds__(256) void k_out(
    const float* __restrict__ x2n, const float* __restrict__ mask,
    float* __restrict__ out)
{
    int z = blockIdx.x;
    int c = threadIdx.x;   // 256
    float s = 0.0f;
    for (int n = 0; n < Nc; n++)
        s += x2n[((size_t)z*Nc + n)*2*Cc + c] * mask[z*Nc + n];
    out[z*2*Cc + c] = s;
}

// ---------------------------------------------------------------------------
extern "C" void kernel_launch(void* const* d_in, const int* in_sizes, int n_in,
                              void* d_out, int out_size, void* d_ws, size_t ws_size,
                              hipStream_t stream)
{
    const int*   features = (const int*)  d_in[0];
    const float* geom     = (const float*)d_in[1];
    const float* mask     = (const float*)d_in[2];
    const float* emb      = (const float*)d_in[3];
    const float* rw[3][3] = {
        {(const float*)d_in[4],  (const float*)d_in[5],  (const float*)d_in[6]},
        {(const float*)d_in[7],  (const float*)d_in[8],  (const float*)d_in[9]},
        {(const float*)d_in[10], (const float*)d_in[11], (const float*)d_in[12]}};
    const float* pw0 = (const float*)d_in[13]; const float* pb0 = (const float*)d_in[14];
    const float* w1a = (const float*)d_in[15]; const float* b1a = (const float*)d_in[16];
    const float* w1b = (const float*)d_in[17]; const float* b1b = (const float*)d_in[18];
    const float* w2a = (const float*)d_in[19]; const float* b2a = (const float*)d_in[20];
    const float* w2b = (const float*)d_in[21]; const float* b2b = (const float*)d_in[22];
    const float* e1w = (const float*)d_in[23]; const float* e1b = (const float*)d_in[24];
    const float* bn1g= (const float*)d_in[25]; const float* bn1b= (const float*)d_in[26];
    const float* e2w = (const float*)d_in[27]; const float* e2b = (const float*)d_in[28];
    const float* bn2g= (const float*)d_in[29]; const float* bn2b= (const float*)d_in[30];

    // workspace layout (floats); total ~13.4M floats = ~53.6 MB
    float* ws     = (float*)d_ws;
    float* h2     = ws;                        // Z*N*N*NH       = 8388608
    float* g      = h2   + 8388608;            // Z*N*NH*64 max  = 4194304
    float* part   = g    + 4194304;            // 16*Z*N*64      =  524288
    float* fA     = part + 524288;             // Z*N*64
    float* fB     = fA   + 32768;
    float* geo_pn = fB   + 32768;
    float* x1     = geo_pn + 32768;            // Z*N*C
    float* x2     = x1   + 65536;              // Z*N*2C
    (void)ws_size; (void)in_sizes; (void)n_in; (void)out_size;

    k_pointnet<<<Zc*Nc, 64, 0, stream>>>(geom, mask, pw0, pb0, w1a, b1a, w1b, b1b,
                                         w2a, b2a, w2b, b2b, features, emb, geo_pn, fA);

    // layer 0: din=16(EMB), dout=32(L0)
    k_gmat<16,32><<<dim3(Zc*Nc/8, (NHc*32)/256), 256, 0, stream>>>(fA, mask, rw[0][2], g);
    k_pairmlp<<<Zc*Nc*Nc/64, 256, 0, stream>>>(geom, rw[0][0], rw[0][1], h2);
    k_gemm3<32><<<dim3(16,8,Zc), 256, 0, stream>>>(h2, g, part);
    k_epilogue<32><<<(Zc*Nc*32 + 255)/256, 256, 0, stream>>>(part, mask, fB);

    // layer 1: din=32, dout=32
    k_gmat<32,32><<<dim3(Zc*Nc/8, (NHc*32)/256), 256, 0, stream>>>(fB, mask, rw[1][2], g);
    k_pairmlp<<<Zc*Nc*Nc/64, 256, 0, stream>>>(geom, rw[1][0], rw[1][1], h2);
    k_gemm3<32><<<dim3(16,8,Zc), 256, 0, stream>>>(h2, g, part);
    k_epilogue<32><<<(Zc*Nc*32 + 255)/256, 256, 0, stream>>>(part, mask, fA);

    // layer 2: din=32, dout=64(MLPH)
    k_gmat<32,64><<<dim3(Zc*Nc/8, (NHc*64)/256), 256, 0, stream>>>(fA, mask, rw[2][2], g);
    k_pairmlp<<<Zc*Nc*Nc/64, 256, 0, stream>>>(geom, rw[2][0], rw[2][1], h2);
    k_gemm3<64><<<dim3(16,8,Zc), 256, 0, stream>>>(h2, g, part);
    k_epilogue<64><<<(Zc*Nc*64 + 255)/256, 256, 0, stream>>>(part, mask, fB);

    // output MLP + per-atom BN + masked sum
    k_x1<<<Zc*Nc, 128, 0, stream>>>(fB, geo_pn, e1w, e1b, x1);
    k_bn<Cc><<<Nc, 256, 0, stream>>>(x1, bn1g, bn1b);
    k_x2<<<Zc*Nc, 256, 0, stream>>>(x1, e2w, e2b, x2);
    k_bn<2*Cc><<<Nc, 256, 0, stream>>>(x2, bn2g, bn2b);
    k_out<<<Zc, 256, 0, stream>>>(x2, mask, (float*)d_out);
}

// Round 3
// 209.857 us; speedup vs baseline: 2.4256x; 1.7851x over previous
//
#include <hip/hip_runtime.h>
#include <math.h>

// Sizes (fixed by the reference)
#define Zc   4
#define Nc   128
#define EMBc 16
#define L0c  32
#define MLPHc 64
#define GEOc 64
#define NBc  32
#define NHc  128
#define Cc   128   // MLPH + GEO

typedef float  f32x4  __attribute__((ext_vector_type(4)));
typedef short  bf16x8 __attribute__((ext_vector_type(8)));

union FragU {
    bf16x8 v;
    unsigned short u[8];
    uint2 q2[2];
};

// activations: sp(x) = softplus(5x)/5 ; ssp = sp - log(2)/5
__device__ __forceinline__ float sp5(float x){
    float y = 5.0f * x;
    float t = fabsf(y);
    return (fmaxf(y, 0.0f) + log1pf(__expf(-t))) * 0.2f;
}
__device__ __forceinline__ float ssp5(float x){
    return sp5(x) - 0.13862943611198906f;
}
// fast variant for MFMA path (bf16 rounding dominates anyway)
__device__ __forceinline__ float ssp5f(float x){
    float y = 5.0f * x;
    float e = __expf(-fabsf(y));
    return (fmaxf(y, 0.0f) + __logf(1.0f + e)) * 0.2f - 0.13862943611198906f;
}

__device__ __forceinline__ unsigned short f2bf(float f){
    unsigned int u = __float_as_uint(f);
    unsigned int r = (u + 0x7FFFu + ((u >> 16) & 1u)) >> 16;
    return (unsigned short)r;
}
__device__ __forceinline__ float bf2f(unsigned short u){
    return __uint_as_float(((unsigned int)u) << 16);
}

// shared k-map for MFMA fragments (must be identical for A-gen and B-pack;
// any bijection of K works as long as both sides agree)
__device__ __forceinline__ int kmap(int l, int e){
    return 4*((l >> 4) & 3) + (e & 3) + 16*(e >> 2);
}

// ---------------------------------------------------------------------------
// Pre-pack radial-MLP weights into per-lane MFMA B-fragment order (bf16),
// folding the 1/sqrt(fan_in) scales.  grid = (80, 3 layers), 256 thr.
__global__ __launch_bounds__(256) void k_packw(
    const float* __restrict__ w00, const float* __restrict__ w10,
    const float* __restrict__ w01, const float* __restrict__ w11,
    const float* __restrict__ w02, const float* __restrict__ w12,
    unsigned short* __restrict__ packs)
{
    int layer = blockIdx.y;
    const float* w0s = (layer == 0) ? w00 : (layer == 1) ? w01 : w02;
    const float* w1s = (layer == 0) ? w10 : (layer == 1) ? w11 : w12;
    unsigned short* p0 = packs + layer*4096;
    unsigned short* p1 = packs + 12288 + layer*16384;
    int idx = blockIdx.x*256 + threadIdx.x;
    if (idx < 4096){
        int t8 = idx >> 9, l = (idx >> 3) & 63, e = idx & 7;
        int k = kmap(l, e);
        int n = (t8 << 4) + (l & 15);
        p0[idx] = f2bf(w0s[k*NHc + n] * 0.17677669529663687f);   // 1/sqrt(32)
    } else {
        int j = idx - 4096;
        int fid = j >> 9, l = (j >> 3) & 63, e = j & 7;
        int kk = fid >> 3, t8 = fid & 7;
        int k = 32*kk + kmap(l, e);
        int n = 16*t8 + (l & 15);
        p1[j] = f2bf(w1s[k*NHc + n] * 0.08838834764831845f);     // 1/sqrt(128)
    }
}

// ---------------------------------------------------------------------------
// ResnetPointnet per atom + embedding lookup.  grid = Z*N blocks, 64 threads.
__global__ __launch_bounds__(64) void k_pointnet(
    const float* __restrict__ geom, const float* __restrict__ mask,
    const float* __restrict__ pw0, const float* __restrict__ pb0,
    const float* __restrict__ w1a, const float* __restrict__ b1a,
    const float* __restrict__ w1b, const float* __restrict__ b1b,
    const float* __restrict__ w2a, const float* __restrict__ b2a,
    const float* __restrict__ w2b, const float* __restrict__ b2b,
    const int*   __restrict__ features, const float* __restrict__ emb,
    float* __restrict__ geo_pn, float* __restrict__ f0)
{
    int zn = blockIdx.x;
    int c  = threadIdx.x;            // 0..63
    __shared__ float cur[GEOc];
    __shared__ float tmp[GEOc];
    float gx = geom[zn*3+0], gy = geom[zn*3+1], gz = geom[zn*3+2];
    float v = fmaf(gx, pw0[0*GEOc+c], fmaf(gy, pw0[1*GEOc+c], fmaf(gz, pw0[2*GEOc+c], pb0[c])));
    const float* WA[2] = {w1a, w2a}; const float* BA[2] = {b1a, b2a};
    const float* WB[2] = {w1b, w2b}; const float* BB[2] = {b1b, b2b};
    #pragma unroll
    for (int blk = 0; blk < 2; blk++){
        cur[c] = v;
        __syncthreads();
        float s = BA[blk][c];
        for (int k = 0; k < GEOc; k++) s = fmaf(fmaxf(cur[k], 0.0f), WA[blk][k*GEOc+c], s);
        tmp[c] = s;
        __syncthreads();
        float s2 = BB[blk][c];
        for (int k = 0; k < GEOc; k++) s2 = fmaf(fmaxf(tmp[k], 0.0f), WB[blk][k*GEOc+c], s2);
        v = v + s2;
        __syncthreads();
    }
    geo_pn[zn*GEOc + c] = v * mask[zn];
    if (c < EMBc){
        int fi = features[zn];
        f0[zn*EMBc + c] = emb[fi*EMBc + c];
    }
}

// ---------------------------------------------------------------------------
// g[z,b,m,i] = sum_j w2[m, i*DIN+j] * f[z,b,j] * mask[z,b] * Y0/(sqrt(NH)*sqrt(N))
// grid = (Z*N/8, NH*DOUT/256), 256 threads; thread owns 1 mi x 8 zb-rows.
template<int DIN, int DOUT>
__global__ __launch_bounds__(256) void k_gmat(
    const float* __restrict__ f, const float* __restrict__ mask,
    const float* __restrict__ w2, float* __restrict__ g)
{
    __shared__ float fsh[8][DIN];
    int t   = threadIdx.x;
    int zb0 = blockIdx.x * 8;
    if (t < 8*DIN){
        int r = t / DIN, j = t % DIN;
        int zb = zb0 + r;
        // Y0/(sqrt(NH)*sqrt(N)) = 0.2820947917738781 / 128
        fsh[r][j] = f[zb*DIN + j] * mask[zb] * 0.0022038655607334227f;
    }
    __syncthreads();
    int mi = blockIdx.y * 256 + t;
    const float* wrow = w2 + (size_t)mi * DIN;
    float s[8];
    #pragma unroll
    for (int r = 0; r < 8; r++) s[r] = 0.0f;
    #pragma unroll
    for (int j4 = 0; j4 < DIN/4; j4++){
        float4 w = *reinterpret_cast<const float4*>(&wrow[j4*4]);
        #pragma unroll
        for (int q = 0; q < 4; q++){
            float wv = reinterpret_cast<const float*>(&w)[q];
            int j = j4*4 + q;
            #pragma unroll
            for (int r = 0; r < 8; r++)
                s[r] = fmaf(fsh[r][j], wv, s[r]);
        }
    }
    #pragma unroll
    for (int r = 0; r < 8; r++)
        g[(size_t)(zb0 + r)*(NHc*DOUT) + mi] = s[r];
}

// ---------------------------------------------------------------------------
// MFMA pair-MLP: basis(32) -> ssp(128) -> ssp(128) -> h2 (bf16 global).
// Block = 64 pairs (fixed z,a; b0..b0+63), 256 threads = 4 waves.
// Wave w owns pairs [16w,16w+16); per wave: 8 n-tiles of 16.
__global__ __launch_bounds__(256) void k_pairmlp(
    const float* __restrict__ geom,
    const unsigned short* __restrict__ wp0,
    const unsigned short* __restrict__ wp1,
    unsigned short* __restrict__ h2)
{
    __shared__ unsigned short h1s[64*128];   // 16 KB, XOR-swizzled [m][k] bf16
    char* lb = (char*)h1s;
    int t   = threadIdx.x;
    int w   = t >> 6;
    int l   = t & 63;
    int g16 = l >> 4;
    int c   = l & 15;
    int p0  = blockIdx.x * 64;
    int z   = p0 >> 14;
    int a   = (p0 >> 7) & 127;
    int b0  = p0 & 127;

    // radius for this lane's A-row pair (redundant across the 4 lane-groups)
    int bp = b0 + 16*w + c;
    float ax = geom[(z*Nc + a)*3 + 0];
    float ay = geom[(z*Nc + a)*3 + 1];
    float az = geom[(z*Nc + a)*3 + 2];
    float dx = geom[(z*Nc + bp)*3 + 0] - ax;
    float dy = geom[(z*Nc + bp)*3 + 1] - ay;
    float dz = geom[(z*Nc + bp)*3 + 2] - az;
    float rm = sqrtf(dx*dx + dy*dy + dz*dz);

    // basis A-fragment, computed in-register (K=32 covered by one frag)
    FragU af;
    #pragma unroll
    for (int e = 0; e < 8; e++){
        int k = kmap(l, e);
        float x = rm*3.1f - (float)k;          // (r - k*step)/step, step=10/31
        float v = 0.0f;
        if (fabsf(x) < 1.0f){ float cc = __cosf(1.57079632679f*x); v = cc*cc; }
        af.u[e] = f2bf(v);
    }

    // phase 1: h1 = ssp(basis @ w0pack)   (scale folded into pack)
    f32x4 acc[8];
    #pragma unroll
    for (int t8 = 0; t8 < 8; t8++) acc[t8] = (f32x4){0.f,0.f,0.f,0.f};
    #pragma unroll
    for (int t8 = 0; t8 < 8; t8++){
        bf16x8 bf = *reinterpret_cast<const bf16x8*>(wp0 + ((t8*64 + l) << 3));
        acc[t8] = __builtin_amdgcn_mfma_f32_16x16x32_bf16(af.v, bf, acc[t8], 0, 0, 0);
    }
    // activation + swizzled LDS write (row m, chan n)
    #pragma unroll
    for (int t8 = 0; t8 < 8; t8++){
        #pragma unroll
        for (int rg = 0; rg < 4; rg++){
            int m = 16*w + 4*g16 + rg;
            int n = 16*t8 + c;
            int off = ((m << 8) + (n << 1)) ^ ((m & 7) << 4);
            *(unsigned short*)(lb + off) = f2bf(ssp5f(acc[t8][rg]));
        }
    }
    __syncthreads();

    // phase 2: h2 = ssp(h1 @ w1pack)
    f32x4 acc2[8];
    #pragma unroll
    for (int t8 = 0; t8 < 8; t8++) acc2[t8] = (f32x4){0.f,0.f,0.f,0.f};
    int mrow = 16*w + c;
    int sw   = (mrow & 7) << 4;
    #pragma unroll
    for (int kk = 0; kk < 4; kk++){
        int ob = (mrow << 8) + (kk << 6) + (g16 << 3);
        FragU a2;
        a2.q2[0] = *(const uint2*)(lb + (ob ^ sw));
        a2.q2[1] = *(const uint2*)(lb + ((ob + 32) ^ sw));
        #pragma unroll
        for (int t8 = 0; t8 < 8; t8++){
            bf16x8 bf = *reinterpret_cast<const bf16x8*>(wp1 + (((kk*8 + t8)*64 + l) << 3));
            acc2[t8] = __builtin_amdgcn_mfma_f32_16x16x32_bf16(a2.v, bf, acc2[t8], 0, 0, 0);
        }
    }
    // activation + bf16 store
    size_t rowbase = ((size_t)((z*Nc + a)*Nc + b0)) * NHc;
    #pragma unroll
    for (int t8 = 0; t8 < 8; t8++){
        #pragma unroll
        for (int rg = 0; rg < 4; rg++){
            int m = 16*w + 4*g16 + rg;
            h2[rowbase + (size_t)m*NHc + 16*t8 + c] = f2bf(ssp5f(acc2[t8][rg]));
        }
    }
}

// ---------------------------------------------------------------------------
// f_partial[s][z][a][i] = sum_{bm in slice s} h2[z,a,bm] * g[z,bm,i]
// grid = (16 slices, 8 a-tiles, Z), 256 threads.  K = N*NH = 16384, 1024/slice.
template<int DOUT>
__global__ __launch_bounds__(256) void k_gemm3(
    const unsigned short* __restrict__ h2, const float* __restrict__ g,
    float* __restrict__ partial)
{
    constexpr int AL = DOUT / 16;       // a's per thread (4 or 2)
    __shared__ float h2sh[16*256];      // 16 a-rows x 256 bm
    int t  = threadIdx.x;
    int s  = blockIdx.x;                // 0..15
    int at = blockIdx.y;                // 0..7
    int z  = blockIdx.z;
    int a0 = at * 16;
    int bm0 = s * 1024;
    int i  = t % DOUT;
    int ag = t / DOUT;
    float acc[AL];
    #pragma unroll
    for (int al = 0; al < AL; al++) acc[al] = 0.0f;
    const float* gz = g + (size_t)z * (Nc*NHc) * DOUT;
    for (int ch = 0; ch < 4; ch++){
        __syncthreads();
        #pragma unroll
        for (int j = 0; j < 16; j++){
            int idx = t + j*256;
            int r = idx >> 8, cc = idx & 255;
            h2sh[idx] = bf2f(h2[(size_t)(z*Nc + a0 + r)*(Nc*NHc) + bm0 + ch*256 + cc]);
        }
        __syncthreads();
        const float* gb = gz + (size_t)(bm0 + ch*256)*DOUT + i;
        for (int bb = 0; bb < 256; bb += 4){
            float4 hv[AL];
            #pragma unroll
            for (int al = 0; al < AL; al++)
                hv[al] = *reinterpret_cast<const float4*>(&h2sh[(ag*AL + al)*256 + bb]);
            #pragma unroll
            for (int q = 0; q < 4; q++){
                float gv = gb[(size_t)(bb + q)*DOUT];
                #pragma unroll
                for (int al = 0; al < AL; al++)
                    acc[al] = fmaf(reinterpret_cast<const float*>(&hv[al])[q], gv, acc[al]);
            }
        }
    }
    #pragma unroll
    for (int al = 0; al < AL; al++){
        int aa = a0 + ag*AL + al;
        partial[(((size_t)s*Zc + z)*Nc + aa)*DOUT + i] = acc[al];
    }
}

// f_next = sp(sum_s partial) * mask
template<int DOUT>
__global__ __launch_bounds__(256) void k_epilogue(
    const float* __restrict__ partial, const float* __restrict__ mask,
    float* __restrict__ fout)
{
    int idx = blockIdx.x*256 + threadIdx.x;
    if (idx >= Zc*Nc*DOUT) return;
    int zn = idx / DOUT;
    float s = 0.0f;
    #pragma unroll
    for (int sl = 0; sl < 16; sl++) s += partial[(size_t)sl*(Zc*Nc*DOUT) + idx];
    fout[idx] = sp5(s) * mask[zn];
}

// ---------------------------------------------------------------------------
// output MLP
__global__ __launch_bounds__(128) void k_x1(
    const float* __restrict__ f3, const float* __restrict__ geo_pn,
    const float* __restrict__ w, const float* __restrict__ b,
    float* __restrict__ x1)
{
    int zn = blockIdx.x;
    int c  = threadIdx.x;   // 128
    __shared__ float feat[Cc];
    feat[c] = (c < MLPHc) ? f3[zn*MLPHc + c] : geo_pn[zn*GEOc + (c - MLPHc)];
    __syncthreads();
    float s = b[c];
    for (int k = 0; k < Cc; k++) s = fmaf(feat[k], w[k*Cc + c], s);
    x1[zn*Cc + c] = s;
}

__global__ __launch_bounds__(256) void k_x2(
    const float* __restrict__ x1n, const float* __restrict__ w,
    const float* __restrict__ b, float* __restrict__ x2)
{
    int zn = blockIdx.x;
    int c  = threadIdx.x;   // 256
    __shared__ float row[Cc];
    if (c < Cc) row[c] = x1n[zn*Cc + c];
    __syncthreads();
    float s = b[c];
    for (int k = 0; k < Cc; k++) s = fmaf(row[k], w[k*2*Cc + c], s);
    x2[zn*2*Cc + c] = s;
}

// BatchNorm1d(natoms) over (Z, C) per atom slot + leaky, in place.
template<int CC>
__global__ __launch_bounds__(256) void k_bn(
    float* __restrict__ x, const float* __restrict__ gamma,
    const float* __restrict__ beta)
{
    int n = blockIdx.x;
    int t = threadIdx.x;
    __shared__ float ssum[4], ssq[4];
    float sum = 0.0f, sq = 0.0f;
    for (int idx = t; idx < Zc*CC; idx += 256){
        int z = idx / CC, c = idx % CC;
        float v = x[((size_t)z*Nc + n)*CC + c];
        sum += v; sq += v*v;
    }
    #pragma unroll
    for (int off = 32; off > 0; off >>= 1){
        sum += __shfl_down(sum, off);
        sq  += __shfl_down(sq,  off);
    }
    if ((t & 63) == 0){ ssum[t >> 6] = sum; ssq[t >> 6] = sq; }
    __syncthreads();
    float tot  = ssum[0] + ssum[1] + ssum[2] + ssum[3];
    float totq = ssq[0]  + ssq[1]  + ssq[2]  + ssq[3];
    const float inv = 1.0f / (float)(Zc*CC);
    float mu   = tot * inv;
    float var  = totq * inv - mu*mu;
    float rstd = rsqrtf(var + 1e-5f);
    float ga = gamma[n], be = beta[n];
    for (int idx = t; idx < Zc*CC; idx += 256){
        int z = idx / CC, c = idx % CC;
        size_t o = ((size_t)z*Nc + n)*CC + c;
        float v = (x[o] - mu) * rstd * ga + be;
        x[o] = v > 0.0f ? v : 0.2f*v;
    }
}

__global__ __launch_bounds__(256) void k_out(
    const float* __restrict__ x2n, const float* __restrict__ mask,
    float* __restrict__ out)
{
    int z = blockIdx.x;
    int c = threadIdx.x;   // 256
    float s = 0.0f;
    for (int n = 0; n < Nc; n++)
        s += x2n[((size_t)z*Nc + n)*2*Cc + c] * mask[z*Nc + n];
    out[z*2*Cc + c] = s;
}

// ---------------------------------------------------------------------------
extern "C" void kernel_launch(void* const* d_in, const int* in_sizes, int n_in,
                              void* d_out, int out_size, void* d_ws, size_t ws_size,
                              hipStream_t stream)
{
    const int*   features = (const int*)  d_in[0];
    const float* geom     = (const float*)d_in[1];
    const float* mask     = (const float*)d_in[2];
    const float* emb      = (const float*)d_in[3];
    const float* rw[3][3] = {
        {(const float*)d_in[4],  (const float*)d_in[5],  (const float*)d_in[6]},
        {(const float*)d_in[7],  (const float*)d_in[8],  (const float*)d_in[9]},
        {(const float*)d_in[10], (const float*)d_in[11], (const float*)d_in[12]}};
    const float* pw0 = (const float*)d_in[13]; const float* pb0 = (const float*)d_in[14];
    const float* w1a = (const float*)d_in[15]; const float* b1a = (const float*)d_in[16];
    const float* w1b = (const float*)d_in[17]; const float* b1b = (const float*)d_in[18];
    const float* w2a = (const float*)d_in[19]; const float* b2a = (const float*)d_in[20];
    const float* w2b = (const float*)d_in[21]; const float* b2b = (const float*)d_in[22];
    const float* e1w = (const float*)d_in[23]; const float* e1b = (const float*)d_in[24];
    const float* bn1g= (const float*)d_in[25]; const float* bn1b= (const float*)d_in[26];
    const float* e2w = (const float*)d_in[27]; const float* e2b = (const float*)d_in[28];
    const float* bn2g= (const float*)d_in[29]; const float* bn2b= (const float*)d_in[30];

    // workspace layout (float units)
    float* ws     = (float*)d_ws;
    unsigned short* h2bf = (unsigned short*)ws;        // Z*N*N*NH bf16 = 4194304 floats
    float* g      = ws   + 4194304;                    // Z*N*NH*64 max = 4194304
    float* part   = g    + 4194304;                    // 16*Z*N*64     =  524288
    float* fA     = part + 524288;                     // Z*N*64
    float* fB     = fA   + 32768;
    float* geo_pn = fB   + 32768;
    float* x1     = geo_pn + 32768;                    // Z*N*C
    float* x2     = x1   + 65536;                      // Z*N*2C = 131072
    unsigned short* packs = (unsigned short*)(x2 + 131072);  // 61440 ushorts
    (void)ws_size; (void)in_sizes; (void)n_in; (void)out_size;

    unsigned short* pk0[3] = {packs, packs + 4096, packs + 8192};
    unsigned short* pk1[3] = {packs + 12288, packs + 12288 + 16384, packs + 12288 + 32768};

    k_packw<<<dim3(80, 3), 256, 0, stream>>>(rw[0][0], rw[0][1], rw[1][0], rw[1][1],
                                             rw[2][0], rw[2][1], packs);

    k_pointnet<<<Zc*Nc, 64, 0, stream>>>(geom, mask, pw0, pb0, w1a, b1a, w1b, b1b,
                                         w2a, b2a, w2b, b2b, features, emb, geo_pn, fA);

    // layer 0: din=16(EMB), dout=32(L0)
    k_gmat<16,32><<<dim3(Zc*Nc/8, (NHc*32)/256), 256, 0, stream>>>(fA, mask, rw[0][2], g);
    k_pairmlp<<<Zc*Nc*Nc/64, 256, 0, stream>>>(geom, pk0[0], pk1[0], h2bf);
    k_gemm3<32><<<dim3(16,8,Zc), 256, 0, stream>>>(h2bf, g, part);
    k_epilogue<32><<<(Zc*Nc*32 + 255)/256, 256, 0, stream>>>(part, mask, fB);

    // layer 1: din=32, dout=32
    k_gmat<32,32><<<dim3(Zc*Nc/8, (NHc*32)/256), 256, 0, stream>>>(fB, mask, rw[1][2], g);
    k_pairmlp<<<Zc*Nc*Nc/64, 256, 0, stream>>>(geom, pk0[1], pk1[1], h2bf);
    k_gemm3<32><<<dim3(16,8,Zc), 256, 0, stream>>>(h2bf, g, part);
    k_epilogue<32><<<(Zc*Nc*32 + 255)/256, 256, 0, stream>>>(part, mask, fA);

    // layer 2: din=32, dout=64(MLPH)
    k_gmat<32,64><<<dim3(Zc*Nc/8, (NHc*64)/256), 256, 0, stream>>>(fA, mask, rw[2][2], g);
    k_pairmlp<<<Zc*Nc*Nc/64, 256, 0, stream>>>(geom, pk0[2], pk1[2], h2bf);
    k_gemm3<64><<<dim3(16,8,Zc), 256, 0, stream>>>(h2bf, g, part);
    k_epilogue<64><<<(Zc*Nc*64 + 255)/256, 256, 0, stream>>>(part, mask, fB);

    // output MLP + per-atom BN + masked sum
    k_x1<<<Zc*Nc, 128, 0, stream>>>(fB, geo_pn, e1w, e1b, x1);
    k_bn<Cc><<<Nc, 256, 0, stream>>>(x1, bn1g, bn1b);
    k_x2<<<Zc*Nc, 256, 0, stream>>>(x1, e2w, e2b, x2);
    k_bn<2*Cc><<<Nc, 256, 0, stream>>>(x2, bn2g, bn2b);
    k_out<<<Zc, 256, 0, stream>>>(x2, mask, (float*)d_out);
}